// Round 7
// baseline (147.796 us; speedup 1.0000x reference)
//
#include <hip/hip_runtime.h>

#define DIMN 32
#define HD   32
#define FN   16
#define FE   8
#define NG   64
#define CAP  64          // bucket capacity (in-degree ~Poisson(16); fallback below)
#define K3T  512
#define K3W  (K3T / 64)  // 8 waves = 8 nodes per block (one node per wave)

// K1: out = relu(x @ lin0_w^T + lin0_b); zero deg/aggfb/u/done.
__global__ __launch_bounds__(256) void k1_out(
    const float* __restrict__ x, const float* __restrict__ lin0_w,
    const float* __restrict__ lin0_b,
    float* __restrict__ outn, float* __restrict__ aggfb, float* __restrict__ u,
    int* __restrict__ deg, int* __restrict__ done, int N)
{
    const int gt = blockIdx.x * 256 + threadIdx.x;
    if (gt >= N * DIMN) return;
    const int n = gt >> 5, d = gt & 31;

    float s = lin0_b[d];
    const float* xr = x + (size_t)n * FN;
    const float* wr = lin0_w + d * FN;
    #pragma unroll
    for (int j = 0; j < FN; ++j) s = fmaf(xr[j], wr[j], s);
    outn[gt] = fmaxf(s, 0.f);

    aggfb[gt] = 0.f;
    if (d == 0) deg[n] = 0;
    if (gt < NG * HD) u[gt] = 0.f;
    if (gt == 0) *done = 0;
}

// Kb: bucket edges by destination: es[dst*CAP+pos] = {e, src}.
// Overflow (statistically never for Poisson(16) vs CAP=64): compute the message
// directly and atomicAdd into aggfb, which K3 adds before relu.
__global__ __launch_bounds__(256) void kb_bucket(
    const int* __restrict__ ei, const float* __restrict__ ea,
    const float* __restrict__ outn, const float* __restrict__ nn_w,
    const float* __restrict__ nn_b,
    int* __restrict__ deg, int2* __restrict__ es, float* __restrict__ aggfb, int E)
{
    const int e = blockIdx.x * 256 + threadIdx.x;
    if (e >= E) return;
    const int src = ei[e];
    const int dst = ei[E + e];
    const int pos = atomicAdd(&deg[dst], 1);
    if (pos < CAP) {
        es[(size_t)dst * CAP + pos] = make_int2(e, src);
    } else {
        float ef[FE];
        #pragma unroll
        for (int f = 0; f < FE; ++f) ef[f] = ea[(size_t)e * FE + f];
        for (int h = 0; h < HD; ++h) {
            float m = 0.f;
            for (int d = 0; d < DIMN; ++d) {
                float wdh = nn_b[d * HD + h];
                #pragma unroll
                for (int f = 0; f < FE; ++f)
                    wdh = fmaf(ef[f], nn_w[(d * HD + h) * FE + f], wdh);
                m = fmaf(outn[(size_t)src * DIMN + d], wdh, m);
            }
            atomicAdd(aggfb + (size_t)dst * HD + h, m);
        }
    }
}

// One edge's contribution (mask already applied to o).
#define EDGE_FMA(o, a) \
    S  = (S + (o));                      \
    T0 = fmaf((o), (a).x, T0);           \
    T1 = fmaf((o), (a).y, T1);           \
    T2 = fmaf((o), (a).z, T2);           \
    T3 = fmaf((o), (a).w, T3);

// One d-slice of the contraction into accumulator A.
#define CONTRIB(DD, A) { \
    const int d_ = d0 + (DD); \
    const float4 ta_ = *(const float4*)&s_T[w * 256 + d_ * 8]; \
    const float4 tb_ = *(const float4*)&s_T[w * 256 + d_ * 8 + 4]; \
    const float2 so_ = s_SO[w * 32 + d_]; \
    const int b_ = d_ * 256 + h; \
    A = fmaf(ta_.x, s_nnw2[b_      ], A); \
    A = fmaf(ta_.y, s_nnw2[b_ +  32], A); \
    A = fmaf(ta_.z, s_nnw2[b_ +  64], A); \
    A = fmaf(ta_.w, s_nnw2[b_ +  96], A); \
    A = fmaf(tb_.x, s_nnw2[b_ + 128], A); \
    A = fmaf(tb_.y, s_nnw2[b_ + 160], A); \
    A = fmaf(tb_.z, s_nnw2[b_ + 192], A); \
    A = fmaf(tb_.w, s_nnw2[b_ + 224], A); \
    A = fmaf(so_.x, s_nnb[d_ * 32 + h], A); \
    A = fmaf(so_.y, s_rw [d_ * 32 + h], A); }

// K3: one node per wave (chunk-8 latency-batched edge loop, LDS contraction,
// block-level pooling) + FUSED HEAD via done-counter. Cross-block protocol uses
// ONLY device-scope atomics + per-wave vmcnt(0): u-atomics complete memory-side
// at the TCC (coherent across XCDs), so NO __threadfence / L2 writeback needed.
__global__ __launch_bounds__(K3T, 8) void k3_gather(
    const float* __restrict__ ea, const float* __restrict__ outn,
    const int2* __restrict__ es, const float* __restrict__ nn_w,
    const float* __restrict__ nn_b, const float* __restrict__ root_w,
    const float* __restrict__ conv_b, const int* __restrict__ deg,
    const float* __restrict__ aggfb, const int* __restrict__ batch,
    const float* __restrict__ lin1_w, const float* __restrict__ lin1_b,
    const float* __restrict__ lin2_w, const float* __restrict__ lin2_b,
    float* __restrict__ u, int* __restrict__ done, float* __restrict__ outp,
    int N, int nblocks)
{
    __shared__ float  s_nnw2[DIMN * FE * HD];  // [(d*8+f)*32 + h]  32 KB
    __shared__ float  s_nnb[DIMN * HD];        // 4 KB
    __shared__ float  s_rw[DIMN * HD];         // 4 KB
    __shared__ float  s_cb[HD];
    __shared__ float  s_T[K3W * 256];          // 8 KB (per-wave T slot)
    __shared__ float2 s_SO[K3W * 32];          // 2 KB (S, out[n]) per wave
    __shared__ float  s_V[K3W * 32];           // 1 KB (per-wave node result)
    __shared__ int    s_G[K3W];
    __shared__ int    s_last;

    const int tid = threadIdx.x;
    for (int i = tid; i < DIMN * FE * HD; i += K3T) {
        const int d = i >> 8, rem = i & 255, hh = rem >> 3, f = rem & 7;
        s_nnw2[(d * 8 + f) * 32 + hh] = nn_w[i];   // nn_w[i] = nn_w[(d*32+hh)*8+f]
    }
    for (int i = tid; i < DIMN * HD; i += K3T) { s_nnb[i] = nn_b[i]; s_rw[i] = root_w[i]; }
    if (tid < HD) s_cb[tid] = conv_b[tid];
    __syncthreads();

    const int l = tid & 63;
    const int h = l & 31;
    const int p = l >> 5;
    const int w = tid >> 6;
    const int n = blockIdx.x * K3W + w;   // one node per wave

    int gval = -1;
    if (n < N) {
        const int nu = __builtin_amdgcn_readfirstlane(n);
        const int dn = min(deg[nu], CAP);          // uniform -> s_load
        const int2* ep = es + (size_t)nu * CAP;
        const int f0 = 4 * p;

        float T0 = 0.f, T1 = 0.f, T2 = 0.f, T3 = 0.f, S = 0.f;

        for (int j0 = 0; j0 < dn; j0 += 8) {
            const int jm = dn - 1;
            // 8 uniform index loads (SGPR), clamped for the tail.
            const int2 E0 = ep[j0];
            const int2 E1 = ep[min(j0 + 1, jm)];
            const int2 E2 = ep[min(j0 + 2, jm)];
            const int2 E3 = ep[min(j0 + 3, jm)];
            const int2 E4 = ep[min(j0 + 4, jm)];
            const int2 E5 = ep[min(j0 + 5, jm)];
            const int2 E6 = ep[min(j0 + 6, jm)];
            const int2 E7 = ep[min(j0 + 7, jm)];

            // 16 independent vector loads, all in flight together.
            const float4 a0 = *(const float4*)(ea + (size_t)E0.x * FE + f0);
            const float4 a1 = *(const float4*)(ea + (size_t)E1.x * FE + f0);
            const float4 a2 = *(const float4*)(ea + (size_t)E2.x * FE + f0);
            const float4 a3 = *(const float4*)(ea + (size_t)E3.x * FE + f0);
            const float4 a4 = *(const float4*)(ea + (size_t)E4.x * FE + f0);
            const float4 a5 = *(const float4*)(ea + (size_t)E5.x * FE + f0);
            const float4 a6 = *(const float4*)(ea + (size_t)E6.x * FE + f0);
            const float4 a7 = *(const float4*)(ea + (size_t)E7.x * FE + f0);
            float o0 = outn[(size_t)E0.y * DIMN + h];
            float o1 = outn[(size_t)E1.y * DIMN + h];
            float o2 = outn[(size_t)E2.y * DIMN + h];
            float o3 = outn[(size_t)E3.y * DIMN + h];
            float o4 = outn[(size_t)E4.y * DIMN + h];
            float o5 = outn[(size_t)E5.y * DIMN + h];
            float o6 = outn[(size_t)E6.y * DIMN + h];
            float o7 = outn[(size_t)E7.y * DIMN + h];

            // Zero-mask clamped tail edges (uniform conditions -> cndmask).
            o1 = (j0 + 1 <= jm) ? o1 : 0.f;
            o2 = (j0 + 2 <= jm) ? o2 : 0.f;
            o3 = (j0 + 3 <= jm) ? o3 : 0.f;
            o4 = (j0 + 4 <= jm) ? o4 : 0.f;
            o5 = (j0 + 5 <= jm) ? o5 : 0.f;
            o6 = (j0 + 6 <= jm) ? o6 : 0.f;
            o7 = (j0 + 7 <= jm) ? o7 : 0.f;

            EDGE_FMA(o0, a0) EDGE_FMA(o1, a1) EDGE_FMA(o2, a2) EDGE_FMA(o3, a3)
            EDGE_FMA(o4, a4) EDGE_FMA(o5, a5) EDGE_FMA(o6, a6) EDGE_FMA(o7, a7)
        }

        // Stage T (lane l -> T[d=h, f0..f0+3]), (S, out[n,d]) for the contraction.
        *(float4*)&s_T[w * 256 + h * 8 + f0] = make_float4(T0, T1, T2, T3);
        if (p == 0) s_SO[w * 32 + h] = make_float2(S, outn[(size_t)nu * DIMN + h]);
        // Same-wave LDS write->read: lockstep + compiler lgkmcnt orders this.

        const float base = aggfb[(size_t)nu * HD + h] + s_cb[h];

        // Contraction: lane (h,p) sums its 16-d half; 4 split accumulator chains.
        float acc0 = 0.f, acc1 = 0.f, acc2 = 0.f, acc3 = 0.f;
        const int d0 = p << 4;
        #pragma unroll
        for (int dd = 0; dd < 16; dd += 4) {
            CONTRIB(dd + 0, acc0)
            CONTRIB(dd + 1, acc1)
            CONTRIB(dd + 2, acc2)
            CONTRIB(dd + 3, acc3)
        }
        float acc = (acc0 + acc1) + (acc2 + acc3);
        acc += __shfl_xor(acc, 32);              // combine the two half-wave d-halves

        const float v = fmaxf(acc + base, 0.f);
        if (p == 0) s_V[w * 32 + h] = v;
        gval = batch[nu];                        // uniform across the wave
    }
    if (l == 0) s_G[w] = gval;
    __syncthreads();

    // Block-level run-length pool over the 8 consecutive nodes (batch sorted):
    // ~1-2 atomic flushes per block instead of one per wave. Wave 0 only.
    if (tid < 32) {
        float accp = 0.f;
        int   gc   = -1;
        #pragma unroll
        for (int ww = 0; ww < K3W; ++ww) {
            const int gg = s_G[ww];
            if (gg >= 0) {
                const float vv = s_V[ww * 32 + tid];
                if (gg != gc) {
                    if (gc >= 0) atomicAdd(u + (size_t)gc * HD + tid, accp);
                    gc = gg;
                    accp = vv;
                } else {
                    accp += vv;
                }
            }
        }
        if (gc >= 0) atomicAdd(u + (size_t)gc * HD + tid, accp);
    }

    // ---- fused head, fence-free protocol ----
    // Wave 0 (which issued ALL of this block's u-atomics) drains its own vmem
    // queue: once retired, the memory-side atomics are globally visible.
    if (tid < 64) asm volatile("s_waitcnt vmcnt(0)" ::: "memory");
    __syncthreads();
    if (tid == 0) s_last = (atomicAdd(done, 1) == nblocks - 1) ? 1 : 0;
    __syncthreads();
    if (s_last && tid < NG) {
        const int g = tid;
        float ur[HD];
        #pragma unroll
        for (int hh = 0; hh < HD; ++hh)
            ur[hh] = atomicAdd(&u[(size_t)g * HD + hh], 0.f);  // memory-side read
        float acc2 = lin2_b[0];
        #pragma unroll
        for (int i = 0; i < 16; ++i) {
            float o = lin1_b[i];
            #pragma unroll
            for (int hh = 0; hh < HD; ++hh)
                o = fmaf(ur[hh], lin1_w[i * HD + hh], o);
            o = fmaxf(o, 0.f);
            acc2 = fmaf(o, lin2_w[i], acc2);
        }
        outp[g] = acc2;
    }
}

extern "C" void kernel_launch(void* const* d_in, const int* in_sizes, int n_in,
                              void* d_out, int out_size, void* d_ws, size_t ws_size,
                              hipStream_t stream)
{
    const float* x      = (const float*)d_in[0];
    const int*   ei     = (const int*)  d_in[1];
    const float* ea     = (const float*)d_in[2];
    const int*   batch  = (const int*)  d_in[3];
    const float* lin0_w = (const float*)d_in[4];
    const float* lin0_b = (const float*)d_in[5];
    const float* nn_w   = (const float*)d_in[6];
    const float* nn_b   = (const float*)d_in[7];
    const float* root_w = (const float*)d_in[8];
    const float* conv_b = (const float*)d_in[9];
    const float* lin1_w = (const float*)d_in[10];
    const float* lin1_b = (const float*)d_in[11];
    const float* lin2_w = (const float*)d_in[12];
    const float* lin2_b = (const float*)d_in[13];

    const int N = in_sizes[0] / FN;   // 12500
    const int E = in_sizes[2] / FE;   // 200000

    float* ws    = (float*)d_ws;
    float* outn  = ws;                           // N*32
    float* aggfb = outn  + (size_t)N * DIMN;     // N*32 (overflow fallback)
    float* u     = aggfb + (size_t)N * DIMN;     // 64*32
    int*   deg   = (int*)(u + (size_t)NG * HD);  // N
    int2*  es    = (int2*)(deg + N);             // N*CAP int2 (8B-aligned)
    int*   done  = (int*)(es + (size_t)N * CAP); // 1

    const int nb1 = (N * DIMN + 255) / 256;      // 1563
    k1_out<<<nb1, 256, 0, stream>>>(x, lin0_w, lin0_b, outn, aggfb, u, deg, done, N);

    const int nbb = (E + 255) / 256;             // 782
    kb_bucket<<<nbb, 256, 0, stream>>>(ei, ea, outn, nn_w, nn_b, deg, es, aggfb, E);

    const int nb3 = (N + K3W - 1) / K3W;         // 1563 (8 nodes / block)
    k3_gather<<<nb3, K3T, 0, stream>>>(ea, outn, es, nn_w, nn_b, root_w, conv_b,
                                       deg, aggfb, batch,
                                       lin1_w, lin1_b, lin2_w, lin2_b,
                                       u, done, (float*)d_out, N, nb3);
}